// Round 1
// baseline (1202.930 us; speedup 1.0000x reference)
//
#include <hip/hip_runtime.h>
#include <cmath>

#define Bq 256
#define Nn 200000
#define Dd 64
#define NCHUNK 1563  // ceil(Nn/128)

__device__ __forceinline__ bool mask_at(const void* m, size_t idx, int isbyte) {
    if (isbyte) return ((const unsigned char*)m)[idx] != 0;
    return ((const unsigned int*)m)[idx] != 0u;
}

// ---------------- kernel 0: detect mask storage (byte-bool vs word) ----------------
__global__ void k0_detect(const unsigned int* __restrict__ mw, int* __restrict__ flag) {
    __shared__ int found;
    if (threadIdx.x == 0) found = 0;
    __syncthreads();
    int f = 0;
    for (int i = threadIdx.x; i < 4096; i += 256) {
        unsigned int w = mw[i];
        if (w >= 2u && w != 0x3F800000u) f = 1;   // byte-packed bools leak into high bytes
    }
    if (f) atomicOr(&found, 1);
    __syncthreads();
    if (threadIdx.x == 0) flag[0] = found;        // 1 = byte bools, 0 = word (int/float)
}

// ---------------- kernel 1: same-waypoint valid counts ----------------
__global__ void k1_count(const void* __restrict__ mask, const int* __restrict__ lib_wp,
                         const int* __restrict__ wp_id, const int* __restrict__ flag,
                         int* __restrict__ cnt) {
    __shared__ int wpb[Bq];
    int tid = threadIdx.x;
    wpb[tid] = wp_id[tid];
    __syncthreads();
    int isb = flag[0];
    int n = blockIdx.x * 256 + tid;
    int wpn = (n < Nn) ? lib_wp[n] : -2147483647;
    for (int b = 0; b < Bq; ++b) {
        bool match = false;
        if (n < Nn)
            match = (wpn == wpb[b]) && !mask_at(mask, (size_t)b * Nn + n, isb);
        unsigned long long bal = __ballot(match);
        if ((tid & 63) == 0 && bal)
            atomicAdd(&cnt[b], (int)__popcll(bal));
    }
}

// ---------------- kernel 2: scores GEMM + filters + softmax partials ----------------
__global__ __launch_bounds__(256) void k2_scores(
    const float* __restrict__ q, const float* __restrict__ lib,
    const void* __restrict__ mask, const int* __restrict__ lib_wp,
    const int* __restrict__ wp_id, const int* __restrict__ cnt,
    const int* __restrict__ flag, const float* __restrict__ log_tau,
    float* __restrict__ attnbuf, float* __restrict__ m_part, float* __restrict__ s_part) {
    __shared__ float qt[64][132];   // [k][b_local], padded (16B-aligned rows)
    __shared__ float lt[64][132];   // [k][n_local]
    __shared__ int wp_l[128];
    __shared__ int wpb_l[128];
    __shared__ int suff_l[128];
    int tid = threadIdx.x;
    int cx = blockIdx.x, by = blockIdx.y;
    int n0 = cx * 128, b0 = by * 128;

    for (int idx = tid; idx < 128 * 64; idx += 256) {        // q: r-inner (LDS-friendly)
        int r = idx & 127, k = idx >> 7;
        qt[k][r] = q[(b0 + r) * 64 + k];
    }
    for (int idx = tid; idx < 128 * 64; idx += 256) {        // lib: coalesced global
        int r = idx >> 6, k = idx & 63;
        int n = n0 + r;
        lt[k][r] = (n < Nn) ? lib[(size_t)n * 64 + k] : 0.0f;
    }
    if (tid < 128) {
        int n = n0 + tid;
        wp_l[tid] = (n < Nn) ? lib_wp[n] : (-2147483647 - 1);
        wpb_l[tid] = wp_id[b0 + tid];
        suff_l[tid] = (cnt[b0 + tid] >= 8) ? 1 : 0;
    }
    __syncthreads();

    int tb = tid >> 4, tn = tid & 15;
    int bl = tb * 8, nl = tn * 8;
    float acc[8][8];
#pragma unroll
    for (int i = 0; i < 8; ++i)
#pragma unroll
        for (int j = 0; j < 8; ++j) acc[i][j] = 0.0f;

#pragma unroll 4
    for (int k = 0; k < 64; ++k) {
        float4 qa = *(const float4*)&qt[k][bl];
        float4 qb = *(const float4*)&qt[k][bl + 4];
        float4 la = *(const float4*)&lt[k][nl];
        float4 lb = *(const float4*)&lt[k][nl + 4];
        float qv[8] = {qa.x, qa.y, qa.z, qa.w, qb.x, qb.y, qb.z, qb.w};
        float lv[8] = {la.x, la.y, la.z, la.w, lb.x, lb.y, lb.z, lb.w};
#pragma unroll
        for (int i = 0; i < 8; ++i)
#pragma unroll
            for (int j = 0; j < 8; ++j) acc[i][j] = fmaf(qv[i], lv[j], acc[i][j]);
    }

    float tau = expf(log_tau[0]);
    tau = fminf(fmaxf(tau, 1e-3f), 10.0f);
    float inv_tau = 1.0f / tau;
    int isb = flag[0];
    const float NEGINF = -__builtin_inff();
    bool vecok = (n0 + 128 <= Nn);

    for (int i = 0; i < 8; ++i) {
        int b = b0 + bl + i;
        int wb = wpb_l[bl + i];
        bool suff = suff_l[bl + i] != 0;
        float sc[8];
#pragma unroll
        for (int j = 0; j < 8; ++j) {
            int n = n0 + nl + j;
            float s = NEGINF;
            if (n < Nn) {
                bool mk = mask_at(mask, (size_t)b * Nn + n, isb);
                bool wpm = (wp_l[nl + j] == wb);
                s = (mk || (suff && !wpm)) ? NEGINF : acc[i][j] * inv_tau;
            }
            sc[j] = s;
        }
        size_t base = (size_t)b * Nn + (size_t)(n0 + nl);
        if (vecok) {
            *(float4*)&attnbuf[base] = make_float4(sc[0], sc[1], sc[2], sc[3]);
            *(float4*)&attnbuf[base + 4] = make_float4(sc[4], sc[5], sc[6], sc[7]);
        } else {
            for (int j = 0; j < 8; ++j)
                if (n0 + nl + j < Nn) attnbuf[base + j] = sc[j];
        }
        float m = sc[0];
#pragma unroll
        for (int j = 1; j < 8; ++j) m = fmaxf(m, sc[j]);
#pragma unroll
        for (int off = 1; off < 16; off <<= 1) m = fmaxf(m, __shfl_xor(m, off, 64));
        float ss = 0.0f;
#pragma unroll
        for (int j = 0; j < 8; ++j)
            if (sc[j] > NEGINF) ss += expf(sc[j] - m);
#pragma unroll
        for (int off = 1; off < 16; off <<= 1) ss += __shfl_xor(ss, off, 64);
        if (tn == 0) {
            m_part[(size_t)b * NCHUNK + cx] = m;
            s_part[(size_t)b * NCHUNK + cx] = ss;
        }
    }
}

// ---------------- kernel 3: combine partials -> M, 1/S ----------------
__global__ void k3_combine(const float* __restrict__ m_part, const float* __restrict__ s_part,
                           float* __restrict__ Mv, float* __restrict__ invSv) {
    int b = blockIdx.x, tid = threadIdx.x;
    __shared__ float red[4];
    __shared__ float Msh;
    const float NEGINF = -__builtin_inff();
    float m = NEGINF;
    for (int c = tid; c < NCHUNK; c += 256) m = fmaxf(m, m_part[(size_t)b * NCHUNK + c]);
#pragma unroll
    for (int off = 1; off < 64; off <<= 1) m = fmaxf(m, __shfl_xor(m, off, 64));
    if ((tid & 63) == 0) red[tid >> 6] = m;
    __syncthreads();
    if (tid == 0) Msh = fmaxf(fmaxf(red[0], red[1]), fmaxf(red[2], red[3]));
    __syncthreads();
    float M = Msh;
    float ss = 0.0f;
    for (int c = tid; c < NCHUNK; c += 256) {
        float mp = m_part[(size_t)b * NCHUNK + c];
        if (mp > NEGINF) ss += s_part[(size_t)b * NCHUNK + c] * expf(mp - M);
    }
#pragma unroll
    for (int off = 1; off < 64; off <<= 1) ss += __shfl_xor(ss, off, 64);
    __syncthreads();
    if ((tid & 63) == 0) red[tid >> 6] = ss;
    __syncthreads();
    if (tid == 0) {
        float S = red[0] + red[1] + red[2] + red[3];
        Mv[b] = M;
        invSv[b] = 1.0f / S;
    }
}

// ---------------- kernel 4: finalize attn in-place + context GEMM partials ----------------
__global__ __launch_bounds__(512) void k4_ctx(
    float* __restrict__ attnbuf, const float* __restrict__ lib,
    const float* __restrict__ Mv, const float* __restrict__ invSv,
    float* __restrict__ ctx_part, int nsub) {
    __shared__ float plds[256 * 66];   // [b][n_local], pad 66 -> conflict-free both ways
    __shared__ float llds[64 * 64];    // [n_local][d]
    int tid = threadIdx.x;
    int w = tid >> 6, lane = tid & 63;
    int b4 = tid >> 3, d8 = tid & 7;
    int bbase = b4 * 4, dbase = d8 * 8;
    float acc[4][8];
#pragma unroll
    for (int i = 0; i < 4; ++i)
#pragma unroll
        for (int j = 0; j < 8; ++j) acc[i][j] = 0.0f;

    long long nstart = (long long)blockIdx.x * nsub * 64;
    for (int sub = 0; sub < nsub; ++sub) {
        long long n0s = nstart + (long long)sub * 64;
        if (n0s >= Nn) break;                               // uniform across block
        for (int idx = tid; idx < 4096; idx += 512) {
            int nl2 = idx >> 6, d = idx & 63;
            long long gn = n0s + nl2;
            llds[nl2 * 64 + d] = (gn < Nn) ? lib[gn * 64 + d] : 0.0f;
        }
        long long gn = n0s + lane;
        bool ok = gn < Nn;
        for (int bi = 0; bi < 32; ++bi) {
            int b = bi * 8 + w;
            float p = 0.0f;
            if (ok) {
                size_t gidx = (size_t)b * Nn + (size_t)gn;
                float s = attnbuf[gidx];
                p = expf(s - Mv[b]) * invSv[b];
                attnbuf[gidx] = p;
            }
            plds[b * 66 + lane] = p;
        }
        __syncthreads();
#pragma unroll 4
        for (int nl = 0; nl < 64; ++nl) {
            float pa0 = plds[(bbase + 0) * 66 + nl];
            float pa1 = plds[(bbase + 1) * 66 + nl];
            float pa2 = plds[(bbase + 2) * 66 + nl];
            float pa3 = plds[(bbase + 3) * 66 + nl];
            float4 la = *(const float4*)&llds[nl * 64 + dbase];
            float4 lb = *(const float4*)&llds[nl * 64 + dbase + 4];
            float pa[4] = {pa0, pa1, pa2, pa3};
            float lv[8] = {la.x, la.y, la.z, la.w, lb.x, lb.y, lb.z, lb.w};
#pragma unroll
            for (int i = 0; i < 4; ++i)
#pragma unroll
                for (int j = 0; j < 8; ++j) acc[i][j] = fmaf(pa[i], lv[j], acc[i][j]);
        }
        __syncthreads();
    }
    size_t base = (size_t)blockIdx.x * (256 * 64);
#pragma unroll
    for (int i = 0; i < 4; ++i) {
        *(float4*)&ctx_part[base + (size_t)(bbase + i) * 64 + dbase] =
            make_float4(acc[i][0], acc[i][1], acc[i][2], acc[i][3]);
        *(float4*)&ctx_part[base + (size_t)(bbase + i) * 64 + dbase + 4] =
            make_float4(acc[i][4], acc[i][5], acc[i][6], acc[i][7]);
    }
}

// ---------------- kernel 5: reduce ctx partials + MLP + prior ----------------
__global__ void k5_mlp(const float* __restrict__ q, const float* __restrict__ ctx_part,
                       int nblk4, const int* __restrict__ action_id,
                       const float* __restrict__ act_emb, const float* __restrict__ W1,
                       const float* __restrict__ b1, const float* __restrict__ W2,
                       const float* __restrict__ b2, const float* __restrict__ wp_prior,
                       const float* __restrict__ plw, float* __restrict__ out) {
    int b = blockIdx.x;
    int j = threadIdx.x;  // 64 threads
    float ctx = 0.0f;
    for (int c = 0; c < nblk4; ++c) ctx += ctx_part[((size_t)c * 256 + b) * 64 + j];
    float acc = b1[j];
    int aid = action_id[b];
    for (int i = 0; i < 64; ++i) acc = fmaf(q[b * 64 + i], W1[i * 64 + j], acc);
    for (int i = 0; i < 64; ++i) acc = fmaf(__shfl(ctx, i, 64), W1[(64 + i) * 64 + j], acc);
    for (int i = 0; i < 6; ++i) acc = fmaf(act_emb[aid * 6 + i], W1[(128 + i) * 64 + j], acc);
    float h1 = 0.5f * acc * (1.0f + erff(acc * 0.70710678118654752f));
    float v = h1 * W2[j];
#pragma unroll
    for (int off = 1; off < 64; off <<= 1) v += __shfl_xor(v, off, 64);
    if (j == 0) {
        float pr = fminf(fmaxf(wp_prior[b], 1e-3f), 1.0f - 1e-3f);
        float pl = logf(pr) - log1pf(-pr);
        out[b] = v + b2[0] + plw[0] * pl;
    }
}

extern "C" void kernel_launch(void* const* d_in, const int* in_sizes, int n_in,
                              void* d_out, int out_size, void* d_ws, size_t ws_size,
                              hipStream_t stream) {
    const float* q = (const float*)d_in[0];
    const float* lib = (const float*)d_in[1];
    const void* mask = d_in[2];
    const int* lib_wp = (const int*)d_in[3];
    const int* wp_id = (const int*)d_in[4];
    const int* action_id = (const int*)d_in[5];
    const float* wp_prior = (const float*)d_in[6];
    const float* act_emb = (const float*)d_in[7];
    const float* W1 = (const float*)d_in[8];
    const float* b1 = (const float*)d_in[9];
    const float* W2 = (const float*)d_in[10];
    const float* b2 = (const float*)d_in[11];
    const float* log_tau = (const float*)d_in[12];
    const float* plw = (const float*)d_in[13];

    float* out = (float*)d_out;
    float* attnbuf = out + 256;  // [256][200000] region, used as score scratch then attn

    char* ws = (char*)d_ws;
    int* flag = (int*)ws;                       // 4 B
    int* cnt = (int*)(ws + 256);                // 1 KB
    float* Mv = (float*)(ws + 2048);            // 1 KB
    float* invSv = (float*)(ws + 3072);         // 1 KB
    float* m_part = (float*)(ws + 4096);        // 256*1563*4
    float* s_part = m_part + (size_t)256 * NCHUNK;
    float* ctx_part = s_part + (size_t)256 * NCHUNK;
    size_t fixed = 4096 + 2ull * 256 * NCHUNK * 4;

    int nsub = 8;
    int nblk4 = (Nn + 8 * 64 - 1) / (8 * 64);           // 391 blocks, ~25.6 MB partials
    if (fixed + (size_t)nblk4 * 65536 > ws_size) {
        nsub = 32; nblk4 = (Nn + 32 * 64 - 1) / (32 * 64);   // 98 blocks, 6.4 MB
    }
    if (fixed + (size_t)nblk4 * 65536 > ws_size) {
        nsub = 125; nblk4 = (Nn + 125 * 64 - 1) / (125 * 64); // 25 blocks, 1.6 MB
    }

    k0_detect<<<1, 256, 0, stream>>>((const unsigned int*)mask, flag);
    hipMemsetAsync(cnt, 0, 256 * sizeof(int), stream);
    k1_count<<<dim3((Nn + 255) / 256), 256, 0, stream>>>(mask, lib_wp, wp_id, flag, cnt);
    k2_scores<<<dim3(NCHUNK, 2), 256, 0, stream>>>(q, lib, mask, lib_wp, wp_id, cnt, flag,
                                                   log_tau, attnbuf, m_part, s_part);
    k3_combine<<<dim3(256), 256, 0, stream>>>(m_part, s_part, Mv, invSv);
    k4_ctx<<<dim3(nblk4), 512, 0, stream>>>(attnbuf, lib, Mv, invSv, ctx_part, nsub);
    k5_mlp<<<dim3(256), 64, 0, stream>>>(q, ctx_part, nblk4, action_id, act_emb, W1, b1, W2,
                                         b2, wp_prior, plw, out);
}

// Round 2
// 559.855 us; speedup vs baseline: 2.1486x; 2.1486x over previous
//
#include <hip/hip_runtime.h>
#include <cmath>

#define Nn 200000
#define Bq 256
#define NCH2 3125   // Nn / 64 (exact)
#define NB1 391     // ceil(Nn / 512)

// ---------------- kernel 0: detect mask storage (byte-bool vs word) ----------------
__global__ void k0_detect(const unsigned int* __restrict__ mw, int* __restrict__ flag) {
    __shared__ int found;
    if (threadIdx.x == 0) found = 0;
    __syncthreads();
    int f = 0;
    for (int i = threadIdx.x; i < 4096; i += 256) {
        unsigned int w = mw[i];
        if (w >= 2u && w != 0x3F800000u) f = 1;   // byte-packed bools leak into high bytes
    }
    if (f) atomicOr(&found, 1);
    __syncthreads();
    if (threadIdx.x == 0) flag[0] = found;        // 1 = byte bools, 0 = word
}

// ---------------- kernel 1: same-waypoint valid counts (per-block partials) ----------------
__global__ __launch_bounds__(256) void k1_count(
    const void* __restrict__ mask, const int* __restrict__ lib_wp,
    const int* __restrict__ wp_id, const int* __restrict__ flag,
    int* __restrict__ cnt_part) {
    __shared__ int wpb_s[256];
    __shared__ int cnt_l[256];
    int tid = threadIdx.x;
    wpb_s[tid] = wp_id[tid];
    cnt_l[tid] = 0;
    __syncthreads();
    int isb = flag[0];
    long long base = (long long)blockIdx.x * 512 + tid * 2;
    bool in0 = base < Nn, in1 = base + 1 < Nn;
    int w0 = in0 ? lib_wp[base] : (-2147483647 - 1);
    int w1 = in1 ? lib_wp[base + 1] : (-2147483647 - 1);
    for (int b = 0; b < 256; ++b) {
        int wb = wpb_s[b];
        bool m0 = false, m1 = false;
        if (in1) {
            if (isb) {
                const unsigned char* mb = (const unsigned char*)mask + (size_t)b * Nn + base;
                unsigned short two = *(const unsigned short*)mb;
                m0 = (w0 == wb) && ((two & 0xFF) == 0);
                m1 = (w1 == wb) && ((two >> 8) == 0);
            } else {
                const unsigned int* mw = (const unsigned int*)mask + (size_t)b * Nn + base;
                m0 = (w0 == wb) && (mw[0] == 0u);
                m1 = (w1 == wb) && (mw[1] == 0u);
            }
        } else if (in0) {
            if (isb) {
                m0 = (w0 == wb) && (((const unsigned char*)mask)[(size_t)b * Nn + base] == 0);
            } else {
                m0 = (w0 == wb) && (((const unsigned int*)mask)[(size_t)b * Nn + base] == 0u);
            }
        }
        unsigned long long bal0 = __ballot(m0);
        unsigned long long bal1 = __ballot(m1);
        if ((tid & 63) == 0) {
            int c = (int)__popcll(bal0) + (int)__popcll(bal1);
            if (c) atomicAdd(&cnt_l[b], c);
        }
    }
    __syncthreads();
    cnt_part[blockIdx.x * 256 + tid] = cnt_l[tid];
}

// ---------------- kernel 1b: reduce count partials ----------------
__global__ void k1b_reduce(const int* __restrict__ cnt_part, int* __restrict__ cnt) {
    int t = threadIdx.x;
    int s = 0;
    for (int c = 0; c < NB1; ++c) s += cnt_part[c * 256 + t];
    cnt[t] = s;
}

// ---------------- kernel 2: scores GEMM (256b x 64n tiles) + filters + softmax partials ----------------
__global__ __launch_bounds__(256, 3) void k2_scores(
    const float* __restrict__ q, const float* __restrict__ lib,
    const void* __restrict__ mask, const int* __restrict__ lib_wp,
    const int* __restrict__ wp_id, const int* __restrict__ cnt,
    const int* __restrict__ flag, const float* __restrict__ log_tau,
    float* __restrict__ attnbuf, float* __restrict__ m_part, float* __restrict__ s_part) {
    __shared__ float qt[32][256];    // [k][b] for current k-half
    __shared__ float lt[32][64];     // [k][n]
    __shared__ int wpb_s[256];
    __shared__ int suff_s[256];
    __shared__ int wp_l[64];
    int tid = threadIdx.x;
    int cx = blockIdx.x;
    int n0 = cx * 64;
    int tb = tid >> 4, tn = tid & 15;

    wpb_s[tid] = wp_id[tid];
    suff_s[tid] = (cnt[tid] >= 8) ? 1 : 0;
    if (tid < 64) wp_l[tid] = lib_wp[n0 + tid];

    float acc[16][4];
#pragma unroll
    for (int i = 0; i < 16; ++i)
#pragma unroll
        for (int j = 0; j < 4; ++j) acc[i][j] = 0.0f;

    for (int kh = 0; kh < 2; ++kh) {
        __syncthreads();   // protect LDS reuse (and initial small-array writes)
        // stage q half: thread stages row 'tid', all 32 k of this half
#pragma unroll
        for (int it = 0; it < 8; ++it) {
            float4 v = *(const float4*)&q[(size_t)tid * 64 + kh * 32 + it * 4];
            qt[it * 4 + 0][tid] = v.x;
            qt[it * 4 + 1][tid] = v.y;
            qt[it * 4 + 2][tid] = v.z;
            qt[it * 4 + 3][tid] = v.w;
        }
        // stage lib half: 64 rows x 32 k
#pragma unroll
        for (int it = 0; it < 2; ++it) {
            int idx = it * 256 + tid;
            int r = idx & 63, kg = idx >> 6;
            float4 v = *(const float4*)&lib[(size_t)(n0 + r) * 64 + kh * 32 + kg * 4];
            lt[kg * 4 + 0][r] = v.x;
            lt[kg * 4 + 1][r] = v.y;
            lt[kg * 4 + 2][r] = v.z;
            lt[kg * 4 + 3][r] = v.w;
        }
        __syncthreads();
#pragma unroll 4
        for (int k = 0; k < 32; ++k) {
            float4 la = *(const float4*)&lt[k][tn * 4];
            const float* lap = (const float*)&la;
#pragma unroll
            for (int f = 0; f < 4; ++f) {
                float4 qf = *(const float4*)&qt[k][f * 64 + tb * 4];
                const float* qp = (const float*)&qf;
#pragma unroll
                for (int i2 = 0; i2 < 4; ++i2)
#pragma unroll
                    for (int j = 0; j < 4; ++j)
                        acc[f * 4 + i2][j] = fmaf(qp[i2], lap[j], acc[f * 4 + i2][j]);
            }
        }
    }

    float tau = expf(log_tau[0]);
    tau = fminf(fmaxf(tau, 1e-3f), 10.0f);
    float inv_tau = 1.0f / tau;
    int isb = flag[0];
    const float NEGINF = -__builtin_inff();

#pragma unroll
    for (int f = 0; f < 4; ++f)
#pragma unroll
        for (int i2 = 0; i2 < 4; ++i2) {
            int b = f * 64 + tb * 4 + i2;
            int r = f * 4 + i2;
            int wb = wpb_s[b];
            bool suff = suff_s[b] != 0;
            bool mk[4];
            if (isb) {
                uchar4 mv = *(const uchar4*)((const unsigned char*)mask + (size_t)b * Nn + n0 + tn * 4);
                mk[0] = mv.x != 0; mk[1] = mv.y != 0; mk[2] = mv.z != 0; mk[3] = mv.w != 0;
            } else {
                uint4 mv = *(const uint4*)((const unsigned int*)mask + (size_t)b * Nn + n0 + tn * 4);
                mk[0] = mv.x != 0u; mk[1] = mv.y != 0u; mk[2] = mv.z != 0u; mk[3] = mv.w != 0u;
            }
            float sc[4];
#pragma unroll
            for (int j = 0; j < 4; ++j) {
                bool wpm = (wp_l[tn * 4 + j] == wb);
                sc[j] = (mk[j] || (suff && !wpm)) ? NEGINF : acc[r][j] * inv_tau;
            }
            *(float4*)&attnbuf[(size_t)b * Nn + n0 + tn * 4] = make_float4(sc[0], sc[1], sc[2], sc[3]);
            float m = fmaxf(fmaxf(sc[0], sc[1]), fmaxf(sc[2], sc[3]));
#pragma unroll
            for (int off = 1; off < 16; off <<= 1) m = fmaxf(m, __shfl_xor(m, off, 16));
            float ss = 0.0f;
#pragma unroll
            for (int j = 0; j < 4; ++j)
                if (sc[j] > NEGINF) ss += __expf(sc[j] - m);
#pragma unroll
            for (int off = 1; off < 16; off <<= 1) ss += __shfl_xor(ss, off, 16);
            if (tn == 0) {
                m_part[(size_t)cx * 256 + b] = m;
                s_part[(size_t)cx * 256 + b] = ss;
            }
        }
}

// ---------------- kernel 3: combine partials -> M, 1/S ----------------
__global__ void k3_combine(const float* __restrict__ m_part, const float* __restrict__ s_part,
                           float* __restrict__ Mv, float* __restrict__ invSv) {
    int b = blockIdx.x, tid = threadIdx.x;
    __shared__ float red[4];
    __shared__ float Msh;
    const float NEGINF = -__builtin_inff();
    float m = NEGINF;
    for (int c = tid; c < NCH2; c += 256) m = fmaxf(m, m_part[(size_t)c * 256 + b]);
#pragma unroll
    for (int off = 1; off < 64; off <<= 1) m = fmaxf(m, __shfl_xor(m, off, 64));
    if ((tid & 63) == 0) red[tid >> 6] = m;
    __syncthreads();
    if (tid == 0) Msh = fmaxf(fmaxf(red[0], red[1]), fmaxf(red[2], red[3]));
    __syncthreads();
    float M = Msh;
    float ss = 0.0f;
    for (int c = tid; c < NCH2; c += 256) {
        float mp = m_part[(size_t)c * 256 + b];
        if (mp > NEGINF) ss += s_part[(size_t)c * 256 + b] * __expf(mp - M);
    }
#pragma unroll
    for (int off = 1; off < 64; off <<= 1) ss += __shfl_xor(ss, off, 64);
    __syncthreads();
    if ((tid & 63) == 0) red[tid >> 6] = ss;
    __syncthreads();
    if (tid == 0) {
        float S = red[0] + red[1] + red[2] + red[3];
        Mv[b] = M;
        invSv[b] = 1.0f / S;
    }
}

// ---------------- kernel 4: finalize attn in-place + context GEMM partials ----------------
__global__ __launch_bounds__(256, 3) void k4_ctx(
    float* __restrict__ attnbuf, const float* __restrict__ lib,
    const float* __restrict__ Mv, const float* __restrict__ invSv,
    float* __restrict__ ctx_part, int nsub, int nbb) {
    __shared__ float plds[128][68];    // [b_local][n_local]
    __shared__ float llds[64 * 64];    // [n_local][d]
    __shared__ float Msh[128], iSsh[128];
    int tid = threadIdx.x;
    int tb = tid >> 4, tn = tid & 15;
    int by = blockIdx.y;
    int b0 = by * 128;
    if (tid < 128) {
        Msh[tid] = Mv[b0 + tid];
        iSsh[tid] = invSv[b0 + tid];
    }
    float acc2[8][4];
#pragma unroll
    for (int a = 0; a < 8; ++a)
#pragma unroll
        for (int j = 0; j < 4; ++j) acc2[a][j] = 0.0f;
    __syncthreads();

    for (int sub = 0; sub < nsub; ++sub) {
        int ns = blockIdx.x * nsub + sub;
        if (ns >= NCH2) break;                       // uniform across block
        long long n0 = (long long)ns * 64;
        // stage lib tile [64][64]
#pragma unroll
        for (int it = 0; it < 4; ++it) {
            int idx = it * 256 + tid;
            int r = idx >> 4, c4 = idx & 15;
            float4 v = *(const float4*)&lib[(size_t)(n0 + r) * 64 + c4 * 4];
            *(float4*)&llds[r * 64 + c4 * 4] = v;
        }
        // stage 1: scores -> p, write back, stash in LDS
#pragma unroll
        for (int f = 0; f < 2; ++f)
#pragma unroll
            for (int i2 = 0; i2 < 4; ++i2) {
                int bl_ = f * 64 + tb * 4 + i2;
                size_t gidx = (size_t)(b0 + bl_) * Nn + (size_t)n0 + tn * 4;
                float4 s4 = *(const float4*)&attnbuf[gidx];
                float M = Msh[bl_], iS = iSsh[bl_];
                float4 p4 = make_float4(__expf(s4.x - M) * iS, __expf(s4.y - M) * iS,
                                        __expf(s4.z - M) * iS, __expf(s4.w - M) * iS);
                *(float4*)&attnbuf[gidx] = p4;
                *(float4*)&plds[bl_][tn * 4] = p4;
            }
        __syncthreads();
        // stage 2: ctx += P * lib
#pragma unroll 4
        for (int n4 = 0; n4 < 16; ++n4) {
            float4 lv[4];
#pragma unroll
            for (int c = 0; c < 4; ++c)
                lv[c] = *(const float4*)&llds[(n4 * 4 + c) * 64 + tn * 4];
#pragma unroll
            for (int f = 0; f < 2; ++f)
#pragma unroll
                for (int i2 = 0; i2 < 4; ++i2) {
                    int a = f * 4 + i2;
                    float4 pa = *(const float4*)&plds[f * 64 + tb * 4 + i2][n4 * 4];
                    const float* pap = (const float*)&pa;
#pragma unroll
                    for (int c = 0; c < 4; ++c) {
                        const float* lvp = (const float*)&lv[c];
#pragma unroll
                        for (int j = 0; j < 4; ++j)
                            acc2[a][j] = fmaf(pap[c], lvp[j], acc2[a][j]);
                    }
                }
        }
        __syncthreads();
    }
    int bflat = by * nbb + blockIdx.x;
    size_t base = (size_t)bflat * 8192;
#pragma unroll
    for (int f = 0; f < 2; ++f)
#pragma unroll
        for (int i2 = 0; i2 < 4; ++i2) {
            int a = f * 4 + i2;
            int bl_ = f * 64 + tb * 4 + i2;
            *(float4*)&ctx_part[base + (size_t)bl_ * 64 + tn * 4] =
                make_float4(acc2[a][0], acc2[a][1], acc2[a][2], acc2[a][3]);
        }
}

// ---------------- kernel 5: reduce ctx partials + MLP + prior ----------------
__global__ void k5_mlp(const float* __restrict__ q, const float* __restrict__ ctx_part,
                       int nbb, const int* __restrict__ action_id,
                       const float* __restrict__ act_emb, const float* __restrict__ W1,
                       const float* __restrict__ b1, const float* __restrict__ W2,
                       const float* __restrict__ b2, const float* __restrict__ wp_prior,
                       const float* __restrict__ plw, float* __restrict__ out) {
    int b = blockIdx.x;
    int j = threadIdx.x;  // 64 threads
    int by = b >> 7, bl_ = b & 127;
    float ctx = 0.0f;
    for (int nb = 0; nb < nbb; ++nb)
        ctx += ctx_part[((size_t)(by * nbb + nb)) * 8192 + (size_t)bl_ * 64 + j];
    float acc = b1[j];
    int aid = action_id[b];
    for (int i = 0; i < 64; ++i) acc = fmaf(q[b * 64 + i], W1[i * 64 + j], acc);
    for (int i = 0; i < 64; ++i) acc = fmaf(__shfl(ctx, i, 64), W1[(64 + i) * 64 + j], acc);
    for (int i = 0; i < 6; ++i) acc = fmaf(act_emb[aid * 6 + i], W1[(128 + i) * 64 + j], acc);
    float h1 = 0.5f * acc * (1.0f + erff(acc * 0.70710678118654752f));
    float v = h1 * W2[j];
#pragma unroll
    for (int off = 1; off < 64; off <<= 1) v += __shfl_xor(v, off, 64);
    if (j == 0) {
        float pr = fminf(fmaxf(wp_prior[b], 1e-3f), 1.0f - 1e-3f);
        float pl = logf(pr) - log1pf(-pr);
        out[b] = v + b2[0] + plw[0] * pl;
    }
}

extern "C" void kernel_launch(void* const* d_in, const int* in_sizes, int n_in,
                              void* d_out, int out_size, void* d_ws, size_t ws_size,
                              hipStream_t stream) {
    const float* q = (const float*)d_in[0];
    const float* lib = (const float*)d_in[1];
    const void* mask = d_in[2];
    const int* lib_wp = (const int*)d_in[3];
    const int* wp_id = (const int*)d_in[4];
    const int* action_id = (const int*)d_in[5];
    const float* wp_prior = (const float*)d_in[6];
    const float* act_emb = (const float*)d_in[7];
    const float* W1 = (const float*)d_in[8];
    const float* b1 = (const float*)d_in[9];
    const float* W2 = (const float*)d_in[10];
    const float* b2 = (const float*)d_in[11];
    const float* log_tau = (const float*)d_in[12];
    const float* plw = (const float*)d_in[13];

    float* out = (float*)d_out;
    float* attnbuf = out + 256;

    char* ws = (char*)d_ws;
    int* flag = (int*)ws;                                   // @0
    int* cnt = (int*)(ws + 1024);                           // 1 KB
    float* Mv = (float*)(ws + 2048);
    float* invSv = (float*)(ws + 3072);
    int* cnt_part = (int*)(ws + 4096);                      // 391*256*4 = 400384
    float* m_part = (float*)(ws + 405504);                  // 3.2 MB
    float* s_part = (float*)(ws + 405504 + 3200000);        // 3.2 MB
    float* ctx_part = (float*)(ws + 405504 + 6400000);
    size_t fixed = 405504 + 6400000;

    int nsub = 8, nbb = (NCH2 + 7) / 8;                     // 391 -> 25.6 MB partials
    if (fixed + (size_t)nbb * 65536 > ws_size) { nsub = 32;  nbb = (NCH2 + 31) / 32; }   // 6.4 MB
    if (fixed + (size_t)nbb * 65536 > ws_size) { nsub = 125; nbb = (NCH2 + 124) / 125; } // 1.6 MB
    if (fixed + (size_t)nbb * 65536 > ws_size) { nsub = NCH2; nbb = 1; }

    k0_detect<<<1, 256, 0, stream>>>((const unsigned int*)mask, flag);
    k1_count<<<dim3(NB1), 256, 0, stream>>>(mask, lib_wp, wp_id, flag, cnt_part);
    k1b_reduce<<<1, 256, 0, stream>>>(cnt_part, cnt);
    k2_scores<<<dim3(NCH2), 256, 0, stream>>>(q, lib, mask, lib_wp, wp_id, cnt, flag,
                                              log_tau, attnbuf, m_part, s_part);
    k3_combine<<<dim3(256), 256, 0, stream>>>(m_part, s_part, Mv, invSv);
    k4_ctx<<<dim3(nbb, 2), 256, 0, stream>>>(attnbuf, lib, Mv, invSv, ctx_part, nsub, nbb);
    k5_mlp<<<dim3(256), 64, 0, stream>>>(q, ctx_part, nbb, action_id, act_emb, W1, b1, W2,
                                         b2, wp_prior, plw, out);
}

// Round 4
// 112.974 us; speedup vs baseline: 10.6479x; 4.9556x over previous
//
#include <hip/hip_runtime.h>
#include <cmath>

#define Nn 200000
#define Bq 256
#define NWP 512
#define NSEG 391   // ceil(Nn/512)

__device__ __forceinline__ bool mask_at(const void* m, size_t idx, int isbyte) {
    if (isbyte) return ((const unsigned char*)m)[idx] != 0;
    return ((const unsigned int*)m)[idx] != 0u;
}

// ---------------- k0: detect mask storage (byte-bool vs word) ----------------
__global__ void k0_detect(const unsigned int* __restrict__ mw, int* __restrict__ flag) {
    __shared__ int found;
    if (threadIdx.x == 0) found = 0;
    __syncthreads();
    int f = 0;
    for (int i = threadIdx.x; i < 4096; i += 256) {
        unsigned int w = mw[i];
        if (w >= 2u && w != 0x3F800000u) f = 1;   // byte-packed bools leak into high bytes
    }
    if (f) atomicOr(&found, 1);
    __syncthreads();
    if (threadIdx.x == 0) flag[0] = found;        // 1 = byte bools, 0 = word
}

// ---------------- kc1: per-segment waypoint histogram ----------------
__global__ __launch_bounds__(512) void kc1_seghist(const int* __restrict__ lib_wp,
                                                   int* __restrict__ seg_cnt) {
    __shared__ int hist[NWP];
    int t = threadIdx.x, seg = blockIdx.x;
    hist[t] = 0;
    __syncthreads();
    int n = seg * 512 + t;
    if (n < Nn) {
        int w = lib_wp[n]; w = min(max(w, 0), NWP - 1);
        atomicAdd(&hist[w], 1);
    }
    __syncthreads();
    seg_cnt[seg * NWP + t] = hist[t];
}

// ---------------- kc2: column-wise exclusive scan (in-place) + bucket offsets ----------------
__global__ __launch_bounds__(512) void kc2_scan(int* __restrict__ seg_cnt,
                                                int* __restrict__ offs) {
    __shared__ int tot[NWP];
    __shared__ int offs_l[NWP + 1];
    int t = threadIdx.x;
    int run = 0;
    for (int seg = 0; seg < NSEG; ++seg) {
        int v = seg_cnt[seg * NWP + t];
        seg_cnt[seg * NWP + t] = run;     // becomes per-(seg,wp) base
        run += v;
    }
    tot[t] = run;
    __syncthreads();
    if (t == 0) {
        int acc = 0;
        for (int w = 0; w < NWP; ++w) { offs_l[w] = acc; acc += tot[w]; }
        offs_l[NWP] = acc;
    }
    __syncthreads();
    offs[t] = offs_l[t];
    if (t == 0) offs[NWP] = offs_l[NWP];
}

// ---------------- kc3: deterministic (stable) scatter into buckets ----------------
__global__ __launch_bounds__(512) void kc3_scatter(const int* __restrict__ lib_wp,
                                                   const int* __restrict__ seg_cnt,
                                                   const int* __restrict__ offs,
                                                   int* __restrict__ bucket) {
    __shared__ int wps[512];
    int t = threadIdx.x, seg = blockIdx.x;
    int n = seg * 512 + t;
    int w = -1;
    if (n < Nn) { w = lib_wp[n]; w = min(max(w, 0), NWP - 1); }
    wps[t] = w;
    __syncthreads();
    if (n < Nn) {
        int r = 0;
        for (int j = 0; j < t; ++j) r += (wps[j] == w) ? 1 : 0;
        bucket[offs[w] + seg_cnt[seg * NWP + w] + r] = n;
    }
}

// ---------------- kd: per-b same-waypoint valid count (bucket-based) ----------------
__global__ __launch_bounds__(256) void kd_count(const void* __restrict__ mask,
                                                const int* __restrict__ wp_id,
                                                const int* __restrict__ offs,
                                                const int* __restrict__ bucket,
                                                const int* __restrict__ flag,
                                                int* __restrict__ cnt, int* __restrict__ suff) {
    __shared__ int red[256];
    int b = blockIdx.x, t = threadIdx.x;
    int isb = flag[0];
    int w = wp_id[b]; w = min(max(w, 0), NWP - 1);
    int off = offs[w], sz = offs[w + 1] - off;
    int c = 0;
    for (int i = t; i < sz; i += 256) {
        int n = bucket[off + i];
        if (!mask_at(mask, (size_t)b * Nn + n, isb)) c++;
    }
    red[t] = c;
    __syncthreads();
    for (int s = 128; s > 0; s >>= 1) {
        if (t < s) red[t] += red[t + s];
        __syncthreads();
    }
    if (t == 0) { cnt[b] = red[0]; suff[b] = (red[0] >= 8) ? 1 : 0; }
}

// ---------------- ke: sparse per-row flash softmax + context + scatter ----------------
// Scores are stashed in attnbuf[b*Nn+n] (b-private -> no cross-block races),
// context accumulated online (flash-style rescale) reusing the staged lib tile.
__global__ __launch_bounds__(256) void ke_sparse(
    const float* __restrict__ q, const float* __restrict__ lib, const void* __restrict__ mask,
    const int* __restrict__ wp_id, const int* __restrict__ offs, const int* __restrict__ bucket,
    const int* __restrict__ flag, const int* __restrict__ suff,
    const float* __restrict__ log_tau,
    float* __restrict__ attnbuf, float* __restrict__ ctxws) {
    int b = blockIdx.x, t = threadIdx.x;
    if (!suff[b]) return;                        // uniform per block
    __shared__ float q_s[64];
    __shared__ float ltile[64 * 65];             // stride 65: conflict-free row reads
    __shared__ int   nbuf[64];
    __shared__ float pbuf[64];
    __shared__ float Msh, Ssh, scale_sh;
    __shared__ float red2[256];
    if (t < 64) q_s[t] = q[b * 64 + t];
    if (t == 0) { Msh = -INFINITY; Ssh = 0.f; }
    int isb = flag[0];
    float tau = expf(log_tau[0]);
    tau = fminf(fmaxf(tau, 1e-3f), 10.0f);
    float inv_tau = 1.0f / tau;
    int w = wp_id[b]; w = min(max(w, 0), NWP - 1);
    int off = offs[w], sz = offs[w + 1] - off;
    int d = t & 63, g = t >> 6;
    float ctxp = 0.f;
    __syncthreads();

    for (int c0 = 0; c0 < sz; c0 += 64) {
        int cn = min(64, sz - c0);
        // stage lib rows of this chunk: thread (i,part) copies 16 floats (scalar LDS stores)
        int i = t >> 2, part = t & 3;
        if (i < cn) {
            int n_i = bucket[off + c0 + i];
            const float* src = &lib[(size_t)n_i * 64 + part * 16];
            float4 v0 = *(const float4*)&src[0];
            float4 v1 = *(const float4*)&src[4];
            float4 v2 = *(const float4*)&src[8];
            float4 v3 = *(const float4*)&src[12];
            float* dst = &ltile[i * 65 + part * 16];
            dst[0] = v0.x;  dst[1] = v0.y;  dst[2] = v0.z;  dst[3] = v0.w;
            dst[4] = v1.x;  dst[5] = v1.y;  dst[6] = v1.z;  dst[7] = v1.w;
            dst[8] = v2.x;  dst[9] = v2.y;  dst[10] = v2.z; dst[11] = v2.w;
            dst[12] = v3.x; dst[13] = v3.y; dst[14] = v3.z; dst[15] = v3.w;
        }
        if (t < 64) nbuf[t] = (t < cn) ? bucket[off + c0 + t] : -1;
        __syncthreads();
        float s = -INFINITY;
        if (t < 64) {
            if (t < cn) {
                int n = nbuf[t];
                if (!mask_at(mask, (size_t)b * Nn + n, isb)) {
                    float acc = 0.f;
#pragma unroll
                    for (int dd = 0; dd < 64; ++dd) acc = fmaf(q_s[dd], ltile[t * 65 + dd], acc);
                    s = acc * inv_tau;
                }
                attnbuf[(size_t)b * Nn + n] = s;       // raw score stash (b-private)
            }
            float m = s;
#pragma unroll
            for (int o = 1; o < 64; o <<= 1) m = fmaxf(m, __shfl_xor(m, o, 64));
            float e = (s > -INFINITY) ? expf(s - m) : 0.f;
#pragma unroll
            for (int o = 1; o < 64; o <<= 1) e += __shfl_xor(e, o, 64);
            if (t == 0) {
                float newM = fmaxf(Msh, m);
                if (newM > -INFINITY) {
                    float sc = expf(Msh - newM);       // Msh=-inf -> 0 (safe)
                    Ssh = Ssh * sc + e * expf(m - newM);
                    Msh = newM;
                    scale_sh = sc;
                } else {
                    scale_sh = 1.f;
                }
            }
        }
        __syncthreads();
        ctxp *= scale_sh;                               // flash rescale of ctx partials
        if (t < 64) pbuf[t] = (s > -INFINITY) ? expf(s - Msh) : 0.f;
        __syncthreads();
        for (int i2 = g; i2 < cn; i2 += 4)
            ctxp = fmaf(pbuf[i2], ltile[i2 * 65 + d], ctxp);
        __syncthreads();                                // protect ltile/pbuf/scale_sh reuse
    }
    float M = Msh, invS = 1.0f / Ssh;
    red2[t] = ctxp;
    __syncthreads();
    if (t < 64)
        ctxws[b * 64 + t] = (red2[t] + red2[64 + t] + red2[128 + t] + red2[192 + t]) * invS;
    // phase 2: normalize stashed scores -> attn probabilities (restores 0 at -inf)
    for (int i3 = t; i3 < sz; i3 += 256) {
        int n = bucket[off + i3];
        size_t gi = (size_t)b * Nn + n;
        float s2 = attnbuf[gi];
        attnbuf[gi] = (s2 > -INFINITY) ? expf(s2 - M) * invS : 0.f;
    }
}

// ---------------- kf: dense fallback for insufficient rows (rare/never) ----------------
__global__ __launch_bounds__(256) void kf_dense(
    const float* __restrict__ q, const float* __restrict__ lib, const void* __restrict__ mask,
    const int* __restrict__ flag, const int* __restrict__ suff,
    const float* __restrict__ log_tau,
    float* __restrict__ attnbuf, float* __restrict__ ctxws) {
    int b = blockIdx.x, t = threadIdx.x;
    if (suff[b]) return;                         // uniform per block
    __shared__ float q_s[64];
    __shared__ float redm[4], reds[4];
    __shared__ float Msh, Ssh;
    __shared__ float pbuf[256];
    if (t < 64) q_s[t] = q[b * 64 + t];
    if (t == 0) { Msh = -INFINITY; Ssh = 0.f; }
    int isb = flag[0];
    float tau = expf(log_tau[0]);
    tau = fminf(fmaxf(tau, 1e-3f), 10.0f);
    float inv_tau = 1.0f / tau;
    __syncthreads();
    // pass 1: scores -> attnbuf, online m/S
    for (int c0 = 0; c0 < Nn; c0 += 256) {
        int n = c0 + t;
        float s = -INFINITY;
        if (n < Nn && !mask_at(mask, (size_t)b * Nn + n, isb)) {
            float acc = 0.f;
#pragma unroll
            for (int dd = 0; dd < 64; dd += 4) {
                float4 v = *(const float4*)&lib[(size_t)n * 64 + dd];
                acc = fmaf(q_s[dd], v.x, acc);
                acc = fmaf(q_s[dd + 1], v.y, acc);
                acc = fmaf(q_s[dd + 2], v.z, acc);
                acc = fmaf(q_s[dd + 3], v.w, acc);
            }
            s = acc * inv_tau;
        }
        if (n < Nn) attnbuf[(size_t)b * Nn + n] = s;
        float m = s;
#pragma unroll
        for (int o = 1; o < 64; o <<= 1) m = fmaxf(m, __shfl_xor(m, o, 64));
        float e = (s > -INFINITY) ? expf(s - m) : 0.f;
#pragma unroll
        for (int o = 1; o < 64; o <<= 1) e += __shfl_xor(e, o, 64);
        if ((t & 63) == 0) { redm[t >> 6] = m; reds[t >> 6] = e; }
        __syncthreads();
        if (t == 0) {
            for (int wv = 0; wv < 4; ++wv) {
                float m2 = redm[wv], e2 = reds[wv];
                if (m2 > -INFINITY) {
                    if (m2 > Msh) { Ssh = Ssh * expf(Msh - m2) + e2; Msh = m2; }
                    else          { Ssh += e2 * expf(m2 - Msh); }
                }
            }
        }
        __syncthreads();
    }
    float M = Msh, invS = 1.0f / Ssh;
    // pass 2: p + context
    int d = t & 63, g = t >> 6;
    float ctxp = 0.f;
    for (int c0 = 0; c0 < Nn; c0 += 256) {
        int n = c0 + t;
        float p = 0.f;
        if (n < Nn) {
            float s = attnbuf[(size_t)b * Nn + n];
            p = (s > -INFINITY) ? expf(s - M) * invS : 0.f;
            attnbuf[(size_t)b * Nn + n] = p;
        }
        pbuf[t] = p;
        __syncthreads();
        int lim = min(256, Nn - c0);
        for (int i2 = g; i2 < lim; i2 += 4) {
            float p2 = pbuf[i2];
            if (p2 != 0.f) ctxp = fmaf(p2, lib[(size_t)(c0 + i2) * 64 + d], ctxp);
        }
        __syncthreads();
    }
    pbuf[t] = ctxp;
    __syncthreads();
    if (t < 64)
        ctxws[b * 64 + t] = pbuf[t] + pbuf[64 + t] + pbuf[128 + t] + pbuf[192 + t];
}

// ---------------- kg: MLP head + prior ----------------
__global__ void kg_mlp(const float* __restrict__ q, const float* __restrict__ ctxws,
                       const int* __restrict__ action_id,
                       const float* __restrict__ act_emb, const float* __restrict__ W1,
                       const float* __restrict__ b1, const float* __restrict__ W2,
                       const float* __restrict__ b2, const float* __restrict__ wp_prior,
                       const float* __restrict__ plw, float* __restrict__ out) {
    int b = blockIdx.x;
    int j = threadIdx.x;  // 64 threads
    float ctx = ctxws[b * 64 + j];
    float acc = b1[j];
    int aid = action_id[b];
    for (int i = 0; i < 64; ++i) acc = fmaf(q[b * 64 + i], W1[i * 64 + j], acc);
    for (int i = 0; i < 64; ++i) acc = fmaf(__shfl(ctx, i, 64), W1[(64 + i) * 64 + j], acc);
    for (int i = 0; i < 6; ++i) acc = fmaf(act_emb[aid * 6 + i], W1[(128 + i) * 64 + j], acc);
    float h1 = 0.5f * acc * (1.0f + erff(acc * 0.70710678118654752f));
    float v = h1 * W2[j];
#pragma unroll
    for (int off = 1; off < 64; off <<= 1) v += __shfl_xor(v, off, 64);
    if (j == 0) {
        float pr = fminf(fmaxf(wp_prior[b], 1e-3f), 1.0f - 1e-3f);
        float pl = logf(pr) - log1pf(-pr);
        out[b] = v + b2[0] + plw[0] * pl;
    }
}

extern "C" void kernel_launch(void* const* d_in, const int* in_sizes, int n_in,
                              void* d_out, int out_size, void* d_ws, size_t ws_size,
                              hipStream_t stream) {
    const float* q = (const float*)d_in[0];
    const float* lib = (const float*)d_in[1];
    const void* mask = d_in[2];
    const int* lib_wp = (const int*)d_in[3];
    const int* wp_id = (const int*)d_in[4];
    const int* action_id = (const int*)d_in[5];
    const float* wp_prior = (const float*)d_in[6];
    const float* act_emb = (const float*)d_in[7];
    const float* W1 = (const float*)d_in[8];
    const float* b1 = (const float*)d_in[9];
    const float* W2 = (const float*)d_in[10];
    const float* b2 = (const float*)d_in[11];
    const float* log_tau = (const float*)d_in[12];
    const float* plw = (const float*)d_in[13];

    float* out = (float*)d_out;
    float* attnbuf = out + 256;

    char* ws = (char*)d_ws;
    int* flag    = (int*)(ws + 0);
    int* cnt     = (int*)(ws + 1024);
    int* suff    = (int*)(ws + 2048);
    int* offs    = (int*)(ws + 4096);        // 513 ints
    int* seg_cnt = (int*)(ws + 8192);        // 391*512 ints = 800768 B
    int* bucket  = (int*)(ws + 851968);      // 200000 ints
    float* ctxws = (float*)(ws + 1703936);   // 256*64 floats

    // zero entire output (logits overwritten by kg; attn zeros are the sparse default)
    hipMemsetAsync(d_out, 0, (size_t)(256 + (size_t)Bq * Nn) * sizeof(float), stream);

    k0_detect<<<1, 256, 0, stream>>>((const unsigned int*)mask, flag);
    kc1_seghist<<<dim3(NSEG), 512, 0, stream>>>(lib_wp, seg_cnt);
    kc2_scan<<<1, 512, 0, stream>>>(seg_cnt, offs);
    kc3_scatter<<<dim3(NSEG), 512, 0, stream>>>(lib_wp, seg_cnt, offs, bucket);
    kd_count<<<dim3(Bq), 256, 0, stream>>>(mask, wp_id, offs, bucket, flag, cnt, suff);
    ke_sparse<<<dim3(Bq), 256, 0, stream>>>(q, lib, mask, wp_id, offs, bucket, flag, suff,
                                            log_tau, attnbuf, ctxws);
    kf_dense<<<dim3(Bq), 256, 0, stream>>>(q, lib, mask, flag, suff, log_tau, attnbuf, ctxws);
    kg_mlp<<<dim3(Bq), 64, 0, stream>>>(q, ctxws, action_id, act_emb, W1, b1, W2, b2,
                                        wp_prior, plw, out);
}

// Round 5
// 105.550 us; speedup vs baseline: 11.3968x; 1.0703x over previous
//
#include <hip/hip_runtime.h>
#include <cmath>

#define Nn 200000
#define Bq 256
#define NWP 512
#define NSEG 391   // ceil(Nn/512)

__device__ __forceinline__ bool mask_at(const void* m, size_t idx, int isbyte) {
    if (isbyte) return ((const unsigned char*)m)[idx] != 0;
    return ((const unsigned int*)m)[idx] != 0u;
}

// ---------------- kz: fast zero-fill of d_out (rocclr fill only hits 1.7 TB/s) ----------------
__global__ __launch_bounds__(256) void kz_fill(float4* __restrict__ p, int n4) {
    int i = blockIdx.x * 256 + threadIdx.x;
    int stride = gridDim.x * 256;
    const float4 z = make_float4(0.f, 0.f, 0.f, 0.f);
    for (; i < n4; i += stride) p[i] = z;
}

// ---------------- k0: detect mask storage (byte-bool vs word) ----------------
__global__ void k0_detect(const unsigned int* __restrict__ mw, int* __restrict__ flag) {
    __shared__ int found;
    if (threadIdx.x == 0) found = 0;
    __syncthreads();
    int f = 0;
    for (int i = threadIdx.x; i < 4096; i += 256) {
        unsigned int w = mw[i];
        if (w >= 2u && w != 0x3F800000u) f = 1;   // byte-packed bools leak into high bytes
    }
    if (f) atomicOr(&found, 1);
    __syncthreads();
    if (threadIdx.x == 0) flag[0] = found;        // 1 = byte bools, 0 = word
}

// ---------------- kc1: per-segment waypoint histogram ----------------
__global__ __launch_bounds__(512) void kc1_seghist(const int* __restrict__ lib_wp,
                                                   int* __restrict__ seg_cnt) {
    __shared__ int hist[NWP];
    int t = threadIdx.x, seg = blockIdx.x;
    hist[t] = 0;
    __syncthreads();
    int n = seg * 512 + t;
    if (n < Nn) {
        int w = lib_wp[n]; w = min(max(w, 0), NWP - 1);
        atomicAdd(&hist[w], 1);
    }
    __syncthreads();
    seg_cnt[seg * NWP + t] = hist[t];
}

// ---------------- kc2a: per-waypoint parallel scan over segments ----------------
// block w: exclusive-scan the 391 per-segment counts of waypoint w (in-place), total -> tot[w]
__global__ __launch_bounds__(512) void kc2a_colscan(int* __restrict__ seg_cnt,
                                                    int* __restrict__ tot) {
    __shared__ int sc[512];
    int t = threadIdx.x, w = blockIdx.x;
    int v = (t < NSEG) ? seg_cnt[t * NWP + w] : 0;
    sc[t] = v;
    __syncthreads();
    for (int off = 1; off < 512; off <<= 1) {
        int x = (t >= off) ? sc[t - off] : 0;
        __syncthreads();
        sc[t] += x;
        __syncthreads();
    }
    if (t < NSEG)
        seg_cnt[t * NWP + w] = (t > 0) ? sc[t - 1] : 0;   // exclusive base
    if (t == 0) tot[w] = sc[NSEG - 1];
}

// ---------------- kc2b: scan waypoint totals -> bucket offsets ----------------
__global__ __launch_bounds__(512) void kc2b_offscan(const int* __restrict__ tot,
                                                    int* __restrict__ offs) {
    __shared__ int sc[512];
    int t = threadIdx.x;
    sc[t] = tot[t];
    __syncthreads();
    for (int off = 1; off < 512; off <<= 1) {
        int x = (t >= off) ? sc[t - off] : 0;
        __syncthreads();
        sc[t] += x;
        __syncthreads();
    }
    offs[t] = (t > 0) ? sc[t - 1] : 0;    // exclusive
    if (t == 0) offs[NWP] = sc[NWP - 1];
}

// ---------------- kc3: deterministic (stable) scatter into buckets ----------------
__global__ __launch_bounds__(512) void kc3_scatter(const int* __restrict__ lib_wp,
                                                   const int* __restrict__ seg_cnt,
                                                   const int* __restrict__ offs,
                                                   int* __restrict__ bucket) {
    __shared__ int wps[512];
    int t = threadIdx.x, seg = blockIdx.x;
    int n = seg * 512 + t;
    int w = -1;
    if (n < Nn) { w = lib_wp[n]; w = min(max(w, 0), NWP - 1); }
    wps[t] = w;
    __syncthreads();
    if (n < Nn) {
        int r = 0;
        for (int j = 0; j < t; ++j) r += (wps[j] == w) ? 1 : 0;
        bucket[offs[w] + seg_cnt[seg * NWP + w] + r] = n;
    }
}

// ---------------- kd: per-b same-waypoint valid count (bucket-based) ----------------
__global__ __launch_bounds__(256) void kd_count(const void* __restrict__ mask,
                                                const int* __restrict__ wp_id,
                                                const int* __restrict__ offs,
                                                const int* __restrict__ bucket,
                                                const int* __restrict__ flag,
                                                int* __restrict__ cnt, int* __restrict__ suff) {
    __shared__ int red[256];
    int b = blockIdx.x, t = threadIdx.x;
    int isb = flag[0];
    int w = wp_id[b]; w = min(max(w, 0), NWP - 1);
    int off = offs[w], sz = offs[w + 1] - off;
    int c = 0;
    for (int i = t; i < sz; i += 256) {
        int n = bucket[off + i];
        if (!mask_at(mask, (size_t)b * Nn + n, isb)) c++;
    }
    red[t] = c;
    __syncthreads();
    for (int s = 128; s > 0; s >>= 1) {
        if (t < s) red[t] += red[t + s];
        __syncthreads();
    }
    if (t == 0) { cnt[b] = red[0]; suff[b] = (red[0] >= 8) ? 1 : 0; }
}

// ---------------- ke: sparse per-row flash softmax + context + scatter ----------------
// Scores are stashed in attnbuf[b*Nn+n] (b-private -> no cross-block races),
// context accumulated online (flash-style rescale) reusing the staged lib tile.
__global__ __launch_bounds__(256) void ke_sparse(
    const float* __restrict__ q, const float* __restrict__ lib, const void* __restrict__ mask,
    const int* __restrict__ wp_id, const int* __restrict__ offs, const int* __restrict__ bucket,
    const int* __restrict__ flag, const int* __restrict__ suff,
    const float* __restrict__ log_tau,
    float* __restrict__ attnbuf, float* __restrict__ ctxws) {
    int b = blockIdx.x, t = threadIdx.x;
    if (!suff[b]) return;                        // uniform per block
    __shared__ float q_s[64];
    __shared__ float ltile[64 * 65];             // stride 65: conflict-free row reads
    __shared__ int   nbuf[64];
    __shared__ float pbuf[64];
    __shared__ float Msh, Ssh, scale_sh;
    __shared__ float red2[256];
    if (t < 64) q_s[t] = q[b * 64 + t];
    if (t == 0) { Msh = -INFINITY; Ssh = 0.f; }
    int isb = flag[0];
    float tau = expf(log_tau[0]);
    tau = fminf(fmaxf(tau, 1e-3f), 10.0f);
    float inv_tau = 1.0f / tau;
    int w = wp_id[b]; w = min(max(w, 0), NWP - 1);
    int off = offs[w], sz = offs[w + 1] - off;
    int d = t & 63, g = t >> 6;
    float ctxp = 0.f;
    __syncthreads();

    for (int c0 = 0; c0 < sz; c0 += 64) {
        int cn = min(64, sz - c0);
        // stage lib rows of this chunk: thread (i,part) copies 16 floats (scalar LDS stores)
        int i = t >> 2, part = t & 3;
        if (i < cn) {
            int n_i = bucket[off + c0 + i];
            const float* src = &lib[(size_t)n_i * 64 + part * 16];
            float4 v0 = *(const float4*)&src[0];
            float4 v1 = *(const float4*)&src[4];
            float4 v2 = *(const float4*)&src[8];
            float4 v3 = *(const float4*)&src[12];
            float* dst = &ltile[i * 65 + part * 16];
            dst[0] = v0.x;  dst[1] = v0.y;  dst[2] = v0.z;  dst[3] = v0.w;
            dst[4] = v1.x;  dst[5] = v1.y;  dst[6] = v1.z;  dst[7] = v1.w;
            dst[8] = v2.x;  dst[9] = v2.y;  dst[10] = v2.z; dst[11] = v2.w;
            dst[12] = v3.x; dst[13] = v3.y; dst[14] = v3.z; dst[15] = v3.w;
        }
        if (t < 64) nbuf[t] = (t < cn) ? bucket[off + c0 + t] : -1;
        __syncthreads();
        float s = -INFINITY;
        if (t < 64) {
            if (t < cn) {
                int n = nbuf[t];
                if (!mask_at(mask, (size_t)b * Nn + n, isb)) {
                    float acc = 0.f;
#pragma unroll
                    for (int dd = 0; dd < 64; ++dd) acc = fmaf(q_s[dd], ltile[t * 65 + dd], acc);
                    s = acc * inv_tau;
                }
                attnbuf[(size_t)b * Nn + n] = s;       // raw score stash (b-private)
            }
            float m = s;
#pragma unroll
            for (int o = 1; o < 64; o <<= 1) m = fmaxf(m, __shfl_xor(m, o, 64));
            float e = (s > -INFINITY) ? expf(s - m) : 0.f;
#pragma unroll
            for (int o = 1; o < 64; o <<= 1) e += __shfl_xor(e, o, 64);
            if (t == 0) {
                float newM = fmaxf(Msh, m);
                if (newM > -INFINITY) {
                    float sc = expf(Msh - newM);       // Msh=-inf -> 0 (safe)
                    Ssh = Ssh * sc + e * expf(m - newM);
                    Msh = newM;
                    scale_sh = sc;
                } else {
                    scale_sh = 1.f;
                }
            }
        }
        __syncthreads();
        ctxp *= scale_sh;                               // flash rescale of ctx partials
        if (t < 64) pbuf[t] = (s > -INFINITY) ? expf(s - Msh) : 0.f;
        __syncthreads();
        for (int i2 = g; i2 < cn; i2 += 4)
            ctxp = fmaf(pbuf[i2], ltile[i2 * 65 + d], ctxp);
        __syncthreads();                                // protect ltile/pbuf/scale_sh reuse
    }
    float M = Msh, invS = 1.0f / Ssh;
    red2[t] = ctxp;
    __syncthreads();
    if (t < 64)
        ctxws[b * 64 + t] = (red2[t] + red2[64 + t] + red2[128 + t] + red2[192 + t]) * invS;
    // phase 2: normalize stashed scores -> attn probabilities (restores 0 at -inf)
    for (int i3 = t; i3 < sz; i3 += 256) {
        int n = bucket[off + i3];
        size_t gi = (size_t)b * Nn + n;
        float s2 = attnbuf[gi];
        attnbuf[gi] = (s2 > -INFINITY) ? expf(s2 - M) * invS : 0.f;
    }
}

// ---------------- kf: dense fallback for insufficient rows (rare/never) ----------------
__global__ __launch_bounds__(256) void kf_dense(
    const float* __restrict__ q, const float* __restrict__ lib, const void* __restrict__ mask,
    const int* __restrict__ flag, const int* __restrict__ suff,
    const float* __restrict__ log_tau,
    float* __restrict__ attnbuf, float* __restrict__ ctxws) {
    int b = blockIdx.x, t = threadIdx.x;
    if (suff[b]) return;                         // uniform per block
    __shared__ float q_s[64];
    __shared__ float redm[4], reds[4];
    __shared__ float Msh, Ssh;
    __shared__ float pbuf[256];
    if (t < 64) q_s[t] = q[b * 64 + t];
    if (t == 0) { Msh = -INFINITY; Ssh = 0.f; }
    int isb = flag[0];
    float tau = expf(log_tau[0]);
    tau = fminf(fmaxf(tau, 1e-3f), 10.0f);
    float inv_tau = 1.0f / tau;
    __syncthreads();
    // pass 1: scores -> attnbuf, online m/S
    for (int c0 = 0; c0 < Nn; c0 += 256) {
        int n = c0 + t;
        float s = -INFINITY;
        if (n < Nn && !mask_at(mask, (size_t)b * Nn + n, isb)) {
            float acc = 0.f;
#pragma unroll
            for (int dd = 0; dd < 64; dd += 4) {
                float4 v = *(const float4*)&lib[(size_t)n * 64 + dd];
                acc = fmaf(q_s[dd], v.x, acc);
                acc = fmaf(q_s[dd + 1], v.y, acc);
                acc = fmaf(q_s[dd + 2], v.z, acc);
                acc = fmaf(q_s[dd + 3], v.w, acc);
            }
            s = acc * inv_tau;
        }
        if (n < Nn) attnbuf[(size_t)b * Nn + n] = s;
        float m = s;
#pragma unroll
        for (int o = 1; o < 64; o <<= 1) m = fmaxf(m, __shfl_xor(m, o, 64));
        float e = (s > -INFINITY) ? expf(s - m) : 0.f;
#pragma unroll
        for (int o = 1; o < 64; o <<= 1) e += __shfl_xor(e, o, 64);
        if ((t & 63) == 0) { redm[t >> 6] = m; reds[t >> 6] = e; }
        __syncthreads();
        if (t == 0) {
            for (int wv = 0; wv < 4; ++wv) {
                float m2 = redm[wv], e2 = reds[wv];
                if (m2 > -INFINITY) {
                    if (m2 > Msh) { Ssh = Ssh * expf(Msh - m2) + e2; Msh = m2; }
                    else          { Ssh += e2 * expf(m2 - Msh); }
                }
            }
        }
        __syncthreads();
    }
    float M = Msh, invS = 1.0f / Ssh;
    // pass 2: p + context
    int d = t & 63, g = t >> 6;
    float ctxp = 0.f;
    for (int c0 = 0; c0 < Nn; c0 += 256) {
        int n = c0 + t;
        float p = 0.f;
        if (n < Nn) {
            float s = attnbuf[(size_t)b * Nn + n];
            p = (s > -INFINITY) ? expf(s - M) * invS : 0.f;
            attnbuf[(size_t)b * Nn + n] = p;
        }
        pbuf[t] = p;
        __syncthreads();
        int lim = min(256, Nn - c0);
        for (int i2 = g; i2 < lim; i2 += 4) {
            float p2 = pbuf[i2];
            if (p2 != 0.f) ctxp = fmaf(p2, lib[(size_t)(c0 + i2) * 64 + d], ctxp);
        }
        __syncthreads();
    }
    pbuf[t] = ctxp;
    __syncthreads();
    if (t < 64)
        ctxws[b * 64 + t] = pbuf[t] + pbuf[64 + t] + pbuf[128 + t] + pbuf[192 + t];
}

// ---------------- kg: MLP head + prior ----------------
__global__ void kg_mlp(const float* __restrict__ q, const float* __restrict__ ctxws,
                       const int* __restrict__ action_id,
                       const float* __restrict__ act_emb, const float* __restrict__ W1,
                       const float* __restrict__ b1, const float* __restrict__ W2,
                       const float* __restrict__ b2, const float* __restrict__ wp_prior,
                       const float* __restrict__ plw, float* __restrict__ out) {
    int b = blockIdx.x;
    int j = threadIdx.x;  // 64 threads
    float ctx = ctxws[b * 64 + j];
    float acc = b1[j];
    int aid = action_id[b];
    for (int i = 0; i < 64; ++i) acc = fmaf(q[b * 64 + i], W1[i * 64 + j], acc);
    for (int i = 0; i < 64; ++i) acc = fmaf(__shfl(ctx, i, 64), W1[(64 + i) * 64 + j], acc);
    for (int i = 0; i < 6; ++i) acc = fmaf(act_emb[aid * 6 + i], W1[(128 + i) * 64 + j], acc);
    float h1 = 0.5f * acc * (1.0f + erff(acc * 0.70710678118654752f));
    float v = h1 * W2[j];
#pragma unroll
    for (int off = 1; off < 64; off <<= 1) v += __shfl_xor(v, off, 64);
    if (j == 0) {
        float pr = fminf(fmaxf(wp_prior[b], 1e-3f), 1.0f - 1e-3f);
        float pl = logf(pr) - log1pf(-pr);
        out[b] = v + b2[0] + plw[0] * pl;
    }
}

extern "C" void kernel_launch(void* const* d_in, const int* in_sizes, int n_in,
                              void* d_out, int out_size, void* d_ws, size_t ws_size,
                              hipStream_t stream) {
    const float* q = (const float*)d_in[0];
    const float* lib = (const float*)d_in[1];
    const void* mask = d_in[2];
    const int* lib_wp = (const int*)d_in[3];
    const int* wp_id = (const int*)d_in[4];
    const int* action_id = (const int*)d_in[5];
    const float* wp_prior = (const float*)d_in[6];
    const float* act_emb = (const float*)d_in[7];
    const float* W1 = (const float*)d_in[8];
    const float* b1 = (const float*)d_in[9];
    const float* W2 = (const float*)d_in[10];
    const float* b2 = (const float*)d_in[11];
    const float* log_tau = (const float*)d_in[12];
    const float* plw = (const float*)d_in[13];

    float* out = (float*)d_out;
    float* attnbuf = out + 256;

    char* ws = (char*)d_ws;
    int* flag    = (int*)(ws + 0);
    int* cnt     = (int*)(ws + 1024);
    int* suff    = (int*)(ws + 2048);
    int* offs    = (int*)(ws + 3072);        // 513 ints -> ends 5124
    int* tot     = (int*)(ws + 6144);        // 512 ints -> ends 8192
    int* seg_cnt = (int*)(ws + 8192);        // 391*512 ints = 800768 B
    int* bucket  = (int*)(ws + 851968);      // 200000 ints
    float* ctxws = (float*)(ws + 1703936);   // 256*64 floats

    // zero entire output (logits overwritten by kg; attn zeros are the sparse default)
    int n4 = (256 + Bq * Nn) / 4;            // 12800064, exact
    kz_fill<<<dim3(2048), 256, 0, stream>>>((float4*)d_out, n4);

    k0_detect<<<1, 256, 0, stream>>>((const unsigned int*)mask, flag);
    kc1_seghist<<<dim3(NSEG), 512, 0, stream>>>(lib_wp, seg_cnt);
    kc2a_colscan<<<dim3(NWP), 512, 0, stream>>>(seg_cnt, tot);
    kc2b_offscan<<<1, 512, 0, stream>>>(tot, offs);
    kc3_scatter<<<dim3(NSEG), 512, 0, stream>>>(lib_wp, seg_cnt, offs, bucket);
    kd_count<<<dim3(Bq), 256, 0, stream>>>(mask, wp_id, offs, bucket, flag, cnt, suff);
    ke_sparse<<<dim3(Bq), 256, 0, stream>>>(q, lib, mask, wp_id, offs, bucket, flag, suff,
                                            log_tau, attnbuf, ctxws);
    kf_dense<<<dim3(Bq), 256, 0, stream>>>(q, lib, mask, flag, suff, log_tau, attnbuf, ctxws);
    kg_mlp<<<dim3(Bq), 64, 0, stream>>>(q, ctxws, action_id, act_emb, W1, b1, W2, b2,
                                        wp_prior, plw, out);
}

// Round 6
// 79.844 us; speedup vs baseline: 15.0660x; 1.3219x over previous
//
#include <hip/hip_runtime.h>
#include <cmath>

#define Nn 200000
#define Bq 256
#define NWP 512
#define NSEG 391   // ceil(Nn/512)
#define CAP 2048   // per-row compact candidate capacity (typ. bucket ~390)

__device__ __forceinline__ bool mask_at(const void* m, size_t idx, int isbyte) {
    if (isbyte) return ((const unsigned char*)m)[idx] != 0;
    return ((const unsigned int*)m)[idx] != 0u;
}

// ---------------- kc1d: per-segment waypoint histogram + (block 0) mask-format detect ----------------
__global__ __launch_bounds__(512) void kc1d(const int* __restrict__ lib_wp,
                                            int* __restrict__ seg_cnt,
                                            const unsigned int* __restrict__ mw,
                                            int* __restrict__ flag) {
    __shared__ int hist[NWP];
    __shared__ int found;
    int t = threadIdx.x, seg = blockIdx.x;
    hist[t] = 0;
    if (t == 0) found = 0;
    __syncthreads();
    if (seg == 0) {
        int f = 0;
        for (int i = t; i < 4096; i += 512) {
            unsigned int w = mw[i];
            if (w >= 2u && w != 0x3F800000u) f = 1;   // byte-packed bools leak into high bytes
        }
        if (f) atomicOr(&found, 1);
    }
    int n = seg * 512 + t;
    if (n < Nn) {
        int w = lib_wp[n]; w = min(max(w, 0), NWP - 1);
        atomicAdd(&hist[w], 1);
    }
    __syncthreads();
    seg_cnt[seg * NWP + t] = hist[t];
    if (seg == 0 && t == 0) flag[0] = found;
}

// ---------------- kc2a: per-waypoint parallel scan over segments ----------------
__global__ __launch_bounds__(512) void kc2a_colscan(int* __restrict__ seg_cnt,
                                                    int* __restrict__ tot) {
    __shared__ int sc[512];
    int t = threadIdx.x, w = blockIdx.x;
    int v = (t < NSEG) ? seg_cnt[t * NWP + w] : 0;
    sc[t] = v;
    __syncthreads();
    for (int off = 1; off < 512; off <<= 1) {
        int x = (t >= off) ? sc[t - off] : 0;
        __syncthreads();
        sc[t] += x;
        __syncthreads();
    }
    if (t < NSEG)
        seg_cnt[t * NWP + w] = (t > 0) ? sc[t - 1] : 0;   // exclusive base
    if (t == 0) tot[w] = sc[NSEG - 1];
}

// ---------------- kc2b: scan waypoint totals -> bucket offsets ----------------
__global__ __launch_bounds__(512) void kc2b_offscan(const int* __restrict__ tot,
                                                    int* __restrict__ offs) {
    __shared__ int sc[512];
    int t = threadIdx.x;
    sc[t] = tot[t];
    __syncthreads();
    for (int off = 1; off < 512; off <<= 1) {
        int x = (t >= off) ? sc[t - off] : 0;
        __syncthreads();
        sc[t] += x;
        __syncthreads();
    }
    offs[t] = (t > 0) ? sc[t - 1] : 0;    // exclusive
    if (t == 0) offs[NWP] = sc[NWP - 1];
}

// ---------------- kc3: deterministic (stable) scatter into buckets ----------------
__global__ __launch_bounds__(512) void kc3_scatter(const int* __restrict__ lib_wp,
                                                   const int* __restrict__ seg_cnt,
                                                   const int* __restrict__ offs,
                                                   int* __restrict__ bucket) {
    __shared__ int wps[512];
    int t = threadIdx.x, seg = blockIdx.x;
    int n = seg * 512 + t;
    int w = -1;
    if (n < Nn) { w = lib_wp[n]; w = min(max(w, 0), NWP - 1); }
    wps[t] = w;
    __syncthreads();
    if (n < Nn) {
        int r = 0;
        for (int j = 0; j < t; ++j) r += (wps[j] == w) ? 1 : 0;
        bucket[offs[w] + seg_cnt[seg * NWP + w] + r] = n;
    }
}

// ---------------- kA: fused zero-fill (slices 1..8) + sparse owner compute (slice 0) ----------------
// Owner writes compact p-values to ws (pv) and ctx to ctxws; never touches attnbuf,
// so fill/compute ordering is a non-issue within the kernel.
__global__ __launch_bounds__(256) void kA(
    const float* __restrict__ q, const float* __restrict__ lib, const void* __restrict__ mask,
    const int* __restrict__ wp_id, const int* __restrict__ offs, const int* __restrict__ bucket,
    const int* __restrict__ flag, const float* __restrict__ log_tau,
    float* __restrict__ attnbuf, float* __restrict__ pv, float* __restrict__ ctxws,
    int* __restrict__ suff, int* __restrict__ ovfl) {
    int bid = blockIdx.x;
    int t = threadIdx.x;
    int b = bid & 255;
    int slice = bid >> 8;             // 0 = owner, 1..8 = fill
    if (slice > 0) {
        float4* rowp = (float4*)(attnbuf + (size_t)b * Nn + (size_t)(slice - 1) * 25000);
        const float4 z = make_float4(0.f, 0.f, 0.f, 0.f);
#pragma unroll 4
        for (int i = t; i < 6250; i += 256) rowp[i] = z;
        return;
    }
    // ---- owner path ----
    __shared__ int   nlist[CAP];
    __shared__ unsigned char vbit[CAP];
    __shared__ float svals[CAP];
    __shared__ float ltile[64 * 65];
    __shared__ float q_s[64];
    __shared__ float red2[256];
    __shared__ int   redc[256];
    __shared__ float pbuf[64];
    __shared__ float Msh, Ssh, scale_sh;

    int isb = flag[0];
    int w = wp_id[b]; w = min(max(w, 0), NWP - 1);
    int off = offs[w], sz = offs[w + 1] - off;
    bool ov = sz > CAP;

    int c = 0;
    if (!ov) {
        for (int i = t; i < sz; i += 256) {
            int n = bucket[off + i];
            nlist[i] = n;
            bool vld = !mask_at(mask, (size_t)b * Nn + n, isb);
            vbit[i] = vld ? 1 : 0;
            c += vld ? 1 : 0;
        }
    } else {
        for (int i = t; i < sz; i += 256) {
            int n = bucket[off + i];
            c += mask_at(mask, (size_t)b * Nn + n, isb) ? 0 : 1;
        }
    }
    redc[t] = c;
    __syncthreads();
    for (int s2 = 128; s2 > 0; s2 >>= 1) {
        if (t < s2) redc[t] += redc[t + s2];
        __syncthreads();
    }
    int cnt = redc[0];
    bool sf = cnt >= 8;
    if (t == 0) { suff[b] = sf ? 1 : 0; ovfl[b] = ov ? 1 : 0; }
    if (!sf || ov) return;            // kB dense-general handles this row

    if (t < 64) q_s[t] = q[b * 64 + t];
    if (t == 0) { Msh = -INFINITY; Ssh = 0.f; }
    float tau = expf(log_tau[0]);
    tau = fminf(fmaxf(tau, 1e-3f), 10.0f);
    float inv_tau = 1.0f / tau;
    int d = t & 63, g = t >> 6;
    float ctxp = 0.f;
    __syncthreads();

    for (int c0 = 0; c0 < sz; c0 += 64) {
        int cn = min(64, sz - c0);
        int i = t >> 2, part = t & 3;
        if (i < cn) {
            int n_i = nlist[c0 + i];
            const float* src = &lib[(size_t)n_i * 64 + part * 16];
            float4 v0 = *(const float4*)&src[0];
            float4 v1 = *(const float4*)&src[4];
            float4 v2 = *(const float4*)&src[8];
            float4 v3 = *(const float4*)&src[12];
            float* dst = &ltile[i * 65 + part * 16];
            dst[0] = v0.x;  dst[1] = v0.y;  dst[2] = v0.z;  dst[3] = v0.w;
            dst[4] = v1.x;  dst[5] = v1.y;  dst[6] = v1.z;  dst[7] = v1.w;
            dst[8] = v2.x;  dst[9] = v2.y;  dst[10] = v2.z; dst[11] = v2.w;
            dst[12] = v3.x; dst[13] = v3.y; dst[14] = v3.z; dst[15] = v3.w;
        }
        __syncthreads();
        float s = -INFINITY;
        if (t < 64) {
            if (t < cn) {
                if (vbit[c0 + t]) {
                    float acc = 0.f;
#pragma unroll
                    for (int dd = 0; dd < 64; ++dd) acc = fmaf(q_s[dd], ltile[t * 65 + dd], acc);
                    s = acc * inv_tau;
                }
                svals[c0 + t] = s;
            }
            float m = s;
#pragma unroll
            for (int o = 1; o < 64; o <<= 1) m = fmaxf(m, __shfl_xor(m, o, 64));
            float e = (s > -INFINITY) ? expf(s - m) : 0.f;
#pragma unroll
            for (int o = 1; o < 64; o <<= 1) e += __shfl_xor(e, o, 64);
            if (t == 0) {
                float newM = fmaxf(Msh, m);
                if (newM > -INFINITY) {
                    float scl = expf(Msh - newM);     // Msh=-inf -> 0 (safe)
                    Ssh = Ssh * scl + e * expf(m - newM);
                    Msh = newM;
                    scale_sh = scl;
                } else {
                    scale_sh = 1.f;
                }
            }
        }
        __syncthreads();
        ctxp *= scale_sh;
        if (t < 64) pbuf[t] = (s > -INFINITY) ? expf(s - Msh) : 0.f;
        __syncthreads();
        for (int i2 = g; i2 < cn; i2 += 4)
            ctxp = fmaf(pbuf[i2], ltile[i2 * 65 + d], ctxp);
        __syncthreads();                  // protect ltile/pbuf/scale_sh reuse
    }
    float M = Msh, invS = 1.0f / Ssh;
    red2[t] = ctxp;
    __syncthreads();
    if (t < 64)
        ctxws[b * 64 + t] = (red2[t] + red2[64 + t] + red2[128 + t] + red2[192 + t]) * invS;
    for (int i = t; i < sz; i += 256) {
        float s2 = svals[i];
        pv[(size_t)b * CAP + i] = (s2 > -INFINITY) ? expf(s2 - M) * invS : 0.f;
    }
}

// ---------------- kB: scatter (or dense-general fallback) + MLP head ----------------
__global__ __launch_bounds__(256) void kB(
    const float* __restrict__ q, const float* __restrict__ lib, const void* __restrict__ mask,
    const int* __restrict__ lib_wp, const int* __restrict__ wp_id,
    const int* __restrict__ offs, const int* __restrict__ bucket,
    const int* __restrict__ flag, const int* __restrict__ suff, const int* __restrict__ ovfl,
    const float* __restrict__ log_tau, const float* __restrict__ pv,
    float* __restrict__ attnbuf, float* __restrict__ ctxws,
    const int* __restrict__ action_id, const float* __restrict__ act_emb,
    const float* __restrict__ W1, const float* __restrict__ b1,
    const float* __restrict__ W2, const float* __restrict__ b2,
    const float* __restrict__ wp_prior, const float* __restrict__ plw,
    float* __restrict__ out) {
    __shared__ float q_s[64];
    __shared__ float redm[4], reds[4];
    __shared__ float Msh, Ssh;
    __shared__ float pbuf2[256];
    int b = blockIdx.x, t = threadIdx.x;
    int sfb = suff[b], ov = ovfl[b];
    int w = wp_id[b]; w = min(max(w, 0), NWP - 1);

    if (sfb && !ov) {
        // sparse scatter of precomputed p over the zero-filled row
        int off = offs[w], sz = offs[w + 1] - off;
        for (int i = t; i < sz; i += 256)
            attnbuf[(size_t)b * Nn + bucket[off + i]] = pv[(size_t)b * CAP + i];
    } else {
        // dense-general evaluator (rare): full reference formula incl. wp filter
        if (t < 64) q_s[t] = q[b * 64 + t];
        if (t == 0) { Msh = -INFINITY; Ssh = 0.f; }
        int isb = flag[0];
        float tau = expf(log_tau[0]);
        tau = fminf(fmaxf(tau, 1e-3f), 10.0f);
        float inv_tau = 1.0f / tau;
        __syncthreads();
        for (int c0 = 0; c0 < Nn; c0 += 256) {
            int n = c0 + t;
            float s = -INFINITY;
            if (n < Nn) {
                bool mk = mask_at(mask, (size_t)b * Nn + n, isb);
                bool wpm = (lib_wp[n] == wp_id[b]);
                if (!mk && !(sfb && !wpm)) {
                    float acc = 0.f;
#pragma unroll
                    for (int dd = 0; dd < 64; dd += 4) {
                        float4 v = *(const float4*)&lib[(size_t)n * 64 + dd];
                        acc = fmaf(q_s[dd], v.x, acc);
                        acc = fmaf(q_s[dd + 1], v.y, acc);
                        acc = fmaf(q_s[dd + 2], v.z, acc);
                        acc = fmaf(q_s[dd + 3], v.w, acc);
                    }
                    s = acc * inv_tau;
                }
                attnbuf[(size_t)b * Nn + n] = s;
            }
            float m = s;
#pragma unroll
            for (int o = 1; o < 64; o <<= 1) m = fmaxf(m, __shfl_xor(m, o, 64));
            float e = (s > -INFINITY) ? expf(s - m) : 0.f;
#pragma unroll
            for (int o = 1; o < 64; o <<= 1) e += __shfl_xor(e, o, 64);
            if ((t & 63) == 0) { redm[t >> 6] = m; reds[t >> 6] = e; }
            __syncthreads();
            if (t == 0) {
                for (int wv = 0; wv < 4; ++wv) {
                    float m2 = redm[wv], e2 = reds[wv];
                    if (m2 > -INFINITY) {
                        if (m2 > Msh) { Ssh = Ssh * expf(Msh - m2) + e2; Msh = m2; }
                        else          { Ssh += e2 * expf(m2 - Msh); }
                    }
                }
            }
            __syncthreads();
        }
        float M = Msh, invS = 1.0f / Ssh;
        int d = t & 63, g = t >> 6;
        float ctxp = 0.f;
        for (int c0 = 0; c0 < Nn; c0 += 256) {
            int n = c0 + t;
            float p = 0.f;
            if (n < Nn) {
                float s = attnbuf[(size_t)b * Nn + n];
                p = (s > -INFINITY) ? expf(s - M) * invS : 0.f;
                attnbuf[(size_t)b * Nn + n] = p;
            }
            pbuf2[t] = p;
            __syncthreads();
            int lim = min(256, Nn - c0);
            for (int i2 = g; i2 < lim; i2 += 4) {
                float p2 = pbuf2[i2];
                if (p2 != 0.f) ctxp = fmaf(p2, lib[(size_t)(c0 + i2) * 64 + d], ctxp);
            }
            __syncthreads();
        }
        pbuf2[t] = ctxp;
        __syncthreads();
        if (t < 64)
            ctxws[b * 64 + t] = pbuf2[t] + pbuf2[64 + t] + pbuf2[128 + t] + pbuf2[192 + t];
    }
    __syncthreads();
    // ---- MLP head + prior (threads 0..63, wave 0) ----
    if (t < 64) {
        int j = t;
        float ctx = ctxws[b * 64 + j];
        float acc = b1[j];
        int aid = action_id[b];
        for (int i = 0; i < 64; ++i) acc = fmaf(q[b * 64 + i], W1[i * 64 + j], acc);
        for (int i = 0; i < 64; ++i) acc = fmaf(__shfl(ctx, i, 64), W1[(64 + i) * 64 + j], acc);
        for (int i = 0; i < 6; ++i) acc = fmaf(act_emb[aid * 6 + i], W1[(128 + i) * 64 + j], acc);
        float h1 = 0.5f * acc * (1.0f + erff(acc * 0.70710678118654752f));
        float v = h1 * W2[j];
#pragma unroll
        for (int o = 1; o < 64; o <<= 1) v += __shfl_xor(v, o, 64);
        if (j == 0) {
            float pr = fminf(fmaxf(wp_prior[b], 1e-3f), 1.0f - 1e-3f);
            float pl = logf(pr) - log1pf(-pr);
            out[b] = v + b2[0] + plw[0] * pl;
        }
    }
}

extern "C" void kernel_launch(void* const* d_in, const int* in_sizes, int n_in,
                              void* d_out, int out_size, void* d_ws, size_t ws_size,
                              hipStream_t stream) {
    const float* q = (const float*)d_in[0];
    const float* lib = (const float*)d_in[1];
    const void* mask = d_in[2];
    const int* lib_wp = (const int*)d_in[3];
    const int* wp_id = (const int*)d_in[4];
    const int* action_id = (const int*)d_in[5];
    const float* wp_prior = (const float*)d_in[6];
    const float* act_emb = (const float*)d_in[7];
    const float* W1 = (const float*)d_in[8];
    const float* b1 = (const float*)d_in[9];
    const float* W2 = (const float*)d_in[10];
    const float* b2 = (const float*)d_in[11];
    const float* log_tau = (const float*)d_in[12];
    const float* plw = (const float*)d_in[13];

    float* out = (float*)d_out;
    float* attnbuf = out + 256;

    char* ws = (char*)d_ws;
    int* flag    = (int*)(ws + 0);
    int* suff    = (int*)(ws + 1024);        // 256 ints
    int* ovfl    = (int*)(ws + 2048);        // 256 ints
    int* offs    = (int*)(ws + 4096);        // 513 ints
    int* tot     = (int*)(ws + 8192);        // 512 ints
    int* seg_cnt = (int*)(ws + 16384);       // 391*512 ints = 800768 B
    int* bucket  = (int*)(ws + 851968);      // 200000 ints
    float* ctxws = (float*)(ws + 1703936);   // 256*64 floats
    float* pv    = (float*)(ws + 2097152);   // 256*CAP floats = 2 MB

    kc1d<<<dim3(NSEG), 512, 0, stream>>>(lib_wp, seg_cnt, (const unsigned int*)mask, flag);
    kc2a_colscan<<<dim3(NWP), 512, 0, stream>>>(seg_cnt, tot);
    kc2b_offscan<<<1, 512, 0, stream>>>(tot, offs);
    kc3_scatter<<<dim3(NSEG), 512, 0, stream>>>(lib_wp, seg_cnt, offs, bucket);
    kA<<<dim3(9 * 256), 256, 0, stream>>>(q, lib, mask, wp_id, offs, bucket, flag, log_tau,
                                          attnbuf, pv, ctxws, suff, ovfl);
    kB<<<dim3(Bq), 256, 0, stream>>>(q, lib, mask, lib_wp, wp_id, offs, bucket, flag, suff,
                                     ovfl, log_tau, pv, attnbuf, ctxws, action_id, act_emb,
                                     W1, b1, W2, b2, wp_prior, plw, out);
}